// Round 5
// baseline (316.678 us; speedup 1.0000x reference)
//
#include <hip/hip_runtime.h>

#define NN 50000
#define NE 800000
#define IN_C 256
#define HID_C 256
#define OUT_C 128

typedef unsigned short u16;
typedef __attribute__((ext_vector_type(8))) short short8;
typedef __attribute__((ext_vector_type(8))) unsigned short ushort8;
typedef __attribute__((ext_vector_type(4))) float f32x4;

__device__ __forceinline__ u16 f2b(float f) {
  unsigned int u = __float_as_uint(f);
  return (u16)((u + 0x7FFFu + ((u >> 16) & 1u)) >> 16);  // RNE
}
__device__ __forceinline__ float b2f(u16 s) {
  return __uint_as_float(((unsigned int)s) << 16);
}

// ---------------- CSR build ----------------

__global__ __launch_bounds__(256) void hist_kernel(const int* __restrict__ col,
                                                   int* __restrict__ cnt, int E) {
  int e = blockIdx.x * blockDim.x + threadIdx.x;
  if (e < E) atomicAdd(&cnt[col[e]], 1);
}

__global__ __launch_bounds__(256) void scan1_kernel(const int* __restrict__ cnt,
                                                    int* __restrict__ bsum, int n) {
  __shared__ int ws[4];
  int i = blockIdx.x * 256 + threadIdx.x;
  int lane = threadIdx.x & 63, wid = threadIdx.x >> 6;
  int v = (i < n) ? cnt[i] : 0;
#pragma unroll
  for (int off = 32; off > 0; off >>= 1) v += __shfl_down(v, off, 64);
  if (lane == 0) ws[wid] = v;
  __syncthreads();
  if (threadIdx.x == 0) bsum[blockIdx.x] = ws[0] + ws[1] + ws[2] + ws[3];
}

__global__ __launch_bounds__(256) void scan2_kernel(const int* __restrict__ bsum,
                                                    int* __restrict__ boff,
                                                    int* __restrict__ row_off,
                                                    int nb, int n) {
  __shared__ int wsum[4], wpre[5];
  int lane = threadIdx.x & 63, wid = threadIdx.x >> 6;
  int v = (threadIdx.x < nb) ? bsum[threadIdx.x] : 0;
  int s = v;
#pragma unroll
  for (int off = 1; off < 64; off <<= 1) {
    int t = __shfl_up(s, off, 64);
    if (lane >= off) s += t;
  }
  if (lane == 63) wsum[wid] = s;
  __syncthreads();
  if (threadIdx.x == 0) {
    int acc = 0;
#pragma unroll
    for (int w = 0; w < 4; ++w) { wpre[w] = acc; acc += wsum[w]; }
    wpre[4] = acc;
  }
  __syncthreads();
  if (threadIdx.x < nb) boff[threadIdx.x] = wpre[wid] + (s - v);
  if (threadIdx.x == 0) row_off[n] = wpre[4];
}

__global__ __launch_bounds__(256) void scan3_kernel(const int* __restrict__ cnt,
                                                    const int* __restrict__ boff,
                                                    int* __restrict__ row_off,
                                                    int* __restrict__ cursor,
                                                    float* __restrict__ dinv, int n) {
  __shared__ int wsum[4], wpre[4];
  int i = blockIdx.x * 256 + threadIdx.x;
  int lane = threadIdx.x & 63, wid = threadIdx.x >> 6;
  int v = (i < n) ? cnt[i] : 0;
  int s = v;
#pragma unroll
  for (int off = 1; off < 64; off <<= 1) {
    int t = __shfl_up(s, off, 64);
    if (lane >= off) s += t;
  }
  if (lane == 63) wsum[wid] = s;
  __syncthreads();
  if (threadIdx.x == 0) {
    int acc = 0;
#pragma unroll
    for (int w = 0; w < 4; ++w) { wpre[w] = acc; acc += wsum[w]; }
  }
  __syncthreads();
  if (i < n) {
    int off = boff[blockIdx.x] + wpre[wid] + (s - v);
    row_off[i] = off;
    cursor[i] = off;
    dinv[i] = rsqrtf((float)(v + 1));
  }
}

// csr stores ONLY the source index; weights are folded into Hscaled rows.
__global__ __launch_bounds__(256) void scatter_kernel(const int* __restrict__ row,
                                                      const int* __restrict__ col,
                                                      int* __restrict__ cursor,
                                                      int* __restrict__ csr, int E) {
  int e = blockIdx.x * blockDim.x + threadIdx.x;
  if (e < E) {
    int c = col[e];
    int p = atomicAdd(&cursor[c], 1);
    csr[p] = row[e];
  }
}

// ---------------- weight convert+transpose ----------------

__global__ __launch_bounds__(256) void convw_kernel(const float* __restrict__ W1,
                                                    const float* __restrict__ W2,
                                                    u16* __restrict__ W1t,
                                                    u16* __restrict__ W2t) {
  int id = blockIdx.x * 256 + threadIdx.x;
  if (id < 256 * 256) {
    int n = id >> 8, k = id & 255;
    W1t[id] = f2b(W1[k * 256 + n]);
  }
  if (id < 128 * 256) {
    int n = id >> 8, k = id & 255;
    W2t[id] = f2b(W2[k * 128 + n]);
  }
}

// ---------------- MFMA GEMM, software-pipelined, row-scaled epilogue ----------------
// C[r,:]bf16 = dscale[r] * (A[r,:] @ Bt^T).  BM=BN=128, BK=32, 4 waves 2x2.

template <bool A_IS_F32>
__global__ __launch_bounds__(256) void gemm_mfma(const void* __restrict__ Ap,
                                                 const u16* __restrict__ Bt,
                                                 const float* __restrict__ dscale,
                                                 u16* __restrict__ C, int M, int N) {
  __shared__ u16 Asl[2][128 * 40];
  __shared__ u16 Bsl[2][128 * 40];
  const int tid = threadIdx.x;
  const int row0 = blockIdx.y * 128;
  const int col0 = blockIdx.x * 128;

  f32x4 acc[4][4] = {};

  const int seg = tid & 7;
  const int rb = tid >> 3;
  const int wave = tid >> 6, lane = tid & 63;
  const int wm = wave >> 1, wn = wave & 1;
  const int qr = lane & 15, quad = lane >> 4;

  float4 aF[4];
  ushort4 aU[4];
  ushort4 bR[4];

  auto load_tiles = [&](int k0) {
    if constexpr (A_IS_F32) {
      const float* A = (const float*)Ap;
#pragma unroll
      for (int i = 0; i < 4; ++i) {
        int gr = row0 + rb + i * 32;
        aF[i] = (gr < M) ? *(const float4*)&A[(size_t)gr * 256 + k0 + seg * 4]
                         : make_float4(0.f, 0.f, 0.f, 0.f);
      }
    } else {
      const u16* A = (const u16*)Ap;
#pragma unroll
      for (int i = 0; i < 4; ++i) {
        int gr = row0 + rb + i * 32;
        aU[i] = (gr < M) ? *(const ushort4*)&A[(size_t)gr * 256 + k0 + seg * 4]
                         : make_ushort4(0, 0, 0, 0);
      }
    }
#pragma unroll
    for (int i = 0; i < 4; ++i) {
      int n = rb + i * 32;
      bR[i] = *(const ushort4*)&Bt[(size_t)(col0 + n) * 256 + k0 + seg * 4];
    }
  };

  auto write_lds = [&](int buf) {
#pragma unroll
    for (int i = 0; i < 4; ++i) {
      int r = rb + i * 32;
      ushort4 u;
      if constexpr (A_IS_F32) {
        u.x = f2b(aF[i].x); u.y = f2b(aF[i].y);
        u.z = f2b(aF[i].z); u.w = f2b(aF[i].w);
      } else {
        u = aU[i];
      }
      *(ushort4*)&Asl[buf][r * 40 + seg * 4] = u;
      *(ushort4*)&Bsl[buf][r * 40 + seg * 4] = bR[i];
    }
  };

  load_tiles(0);
  write_lds(0);
  __syncthreads();

#pragma unroll
  for (int it = 0; it < 8; ++it) {
    const int cur = it & 1;
    if (it < 7) load_tiles((it + 1) * 32);

    short8 afr[4], bfr[4];
#pragma unroll
    for (int mt = 0; mt < 4; ++mt)
      afr[mt] = *(const short8*)&Asl[cur][(wm * 64 + mt * 16 + qr) * 40 + quad * 8];
#pragma unroll
    for (int nt = 0; nt < 4; ++nt)
      bfr[nt] = *(const short8*)&Bsl[cur][(wn * 64 + nt * 16 + qr) * 40 + quad * 8];
#pragma unroll
    for (int mt = 0; mt < 4; ++mt)
#pragma unroll
      for (int nt = 0; nt < 4; ++nt)
        acc[mt][nt] = __builtin_amdgcn_mfma_f32_16x16x32_bf16(afr[mt], bfr[nt], acc[mt][nt], 0, 0, 0);

    if (it < 7) {
      write_lds(1 - cur);
      __syncthreads();
    }
  }

#pragma unroll
  for (int mt = 0; mt < 4; ++mt) {
#pragma unroll
    for (int i = 0; i < 4; ++i) {
      int gr = row0 + wm * 64 + mt * 16 + quad * 4 + i;
      if (gr < M) {
        float sc = dscale[gr];
#pragma unroll
        for (int nt = 0; nt < 4; ++nt) {
          int gc = col0 + wn * 64 + nt * 16 + qr;
          C[(size_t)gr * N + gc] = f2b(acc[mt][nt][i] * sc);
        }
      }
    }
  }
}

// ---------------- aggregation: weightless sum of pre-scaled rows ----------------
// out[v] = dinv[v] * (sum_{src in N(v)} Hs[src] + Hs[v]) + bias   (+ optional relu)

// 256 ch: 2 nodes/wave, 32 lanes x 8 ch, 8x unrolled gathers
__global__ __launch_bounds__(256) void agg256_bf(const u16* __restrict__ h,
                                                 const int* __restrict__ row_off,
                                                 const int* __restrict__ csr,
                                                 const float* __restrict__ dinv,
                                                 const float* __restrict__ bias,
                                                 u16* __restrict__ out, int n) {
  int wave = threadIdx.x >> 6;
  int lane = threadIdx.x & 63;
  int half = lane >> 5;
  int sl = lane & 31;
  int v = blockIdx.x * 8 + wave * 2 + half;
  if (v >= n) return;
  int beg = row_off[v], end = row_off[v + 1];
  float a[8] = {};
  int e = beg;
  for (; e + 7 < end; e += 8) {
    int s[8];
#pragma unroll
    for (int j = 0; j < 8; ++j) s[j] = csr[e + j];
    ushort8 g[8];
#pragma unroll
    for (int j = 0; j < 8; ++j)
      g[j] = *(const ushort8*)&h[(size_t)s[j] * 256 + sl * 8];
#pragma unroll
    for (int j = 0; j < 8; ++j)
#pragma unroll
      for (int i = 0; i < 8; ++i) a[i] += b2f((u16)g[j][i]);
  }
  for (; e + 1 < end; e += 2) {
    int s0 = csr[e], s1 = csr[e + 1];
    ushort8 g0 = *(const ushort8*)&h[(size_t)s0 * 256 + sl * 8];
    ushort8 g1 = *(const ushort8*)&h[(size_t)s1 * 256 + sl * 8];
#pragma unroll
    for (int i = 0; i < 8; ++i) a[i] += b2f((u16)g0[i]) + b2f((u16)g1[i]);
  }
  if (e < end) {
    int s0 = csr[e];
    ushort8 g0 = *(const ushort8*)&h[(size_t)s0 * 256 + sl * 8];
#pragma unroll
    for (int i = 0; i < 8; ++i) a[i] += b2f((u16)g0[i]);
  }
  ushort8 hs = *(const ushort8*)&h[(size_t)v * 256 + sl * 8];
#pragma unroll
  for (int i = 0; i < 8; ++i) a[i] += b2f((u16)hs[i]);
  float dv = dinv[v];
  float4 bv0 = *(const float4*)&bias[sl * 8];
  float4 bv1 = *(const float4*)&bias[sl * 8 + 4];
  float bb[8] = {bv0.x, bv0.y, bv0.z, bv0.w, bv1.x, bv1.y, bv1.z, bv1.w};
  ushort8 o;
#pragma unroll
  for (int i = 0; i < 8; ++i) {
    float r = fmaxf(a[i] * dv + bb[i], 0.f);
    o[i] = (short)f2b(r);
  }
  *(ushort8*)&out[(size_t)v * 256 + sl * 8] = o;
}

// 128 ch: 4 nodes/wave, 16 lanes x 8 ch, 8x unrolled; fp32 output, no relu
__global__ __launch_bounds__(256) void agg128_bf(const u16* __restrict__ h,
                                                 const int* __restrict__ row_off,
                                                 const int* __restrict__ csr,
                                                 const float* __restrict__ dinv,
                                                 const float* __restrict__ bias,
                                                 float* __restrict__ out, int n) {
  int wave = threadIdx.x >> 6;
  int lane = threadIdx.x & 63;
  int quarter = lane >> 4;
  int sl = lane & 15;
  int v = blockIdx.x * 16 + wave * 4 + quarter;
  if (v >= n) return;
  int beg = row_off[v], end = row_off[v + 1];
  float a[8] = {};
  int e = beg;
  for (; e + 7 < end; e += 8) {
    int s[8];
#pragma unroll
    for (int j = 0; j < 8; ++j) s[j] = csr[e + j];
    ushort8 g[8];
#pragma unroll
    for (int j = 0; j < 8; ++j)
      g[j] = *(const ushort8*)&h[(size_t)s[j] * 128 + sl * 8];
#pragma unroll
    for (int j = 0; j < 8; ++j)
#pragma unroll
      for (int i = 0; i < 8; ++i) a[i] += b2f((u16)g[j][i]);
  }
  for (; e + 1 < end; e += 2) {
    int s0 = csr[e], s1 = csr[e + 1];
    ushort8 g0 = *(const ushort8*)&h[(size_t)s0 * 128 + sl * 8];
    ushort8 g1 = *(const ushort8*)&h[(size_t)s1 * 128 + sl * 8];
#pragma unroll
    for (int i = 0; i < 8; ++i) a[i] += b2f((u16)g0[i]) + b2f((u16)g1[i]);
  }
  if (e < end) {
    int s0 = csr[e];
    ushort8 g0 = *(const ushort8*)&h[(size_t)s0 * 128 + sl * 8];
#pragma unroll
    for (int i = 0; i < 8; ++i) a[i] += b2f((u16)g0[i]);
  }
  ushort8 hs = *(const ushort8*)&h[(size_t)v * 128 + sl * 8];
#pragma unroll
  for (int i = 0; i < 8; ++i) a[i] += b2f((u16)hs[i]);
  float dv = dinv[v];
  float4 bv0 = *(const float4*)&bias[sl * 8];
  float4 bv1 = *(const float4*)&bias[sl * 8 + 4];
  float bb[8] = {bv0.x, bv0.y, bv0.z, bv0.w, bv1.x, bv1.y, bv1.z, bv1.w};
  float o[8];
#pragma unroll
  for (int i = 0; i < 8; ++i) o[i] = a[i] * dv + bb[i];
  *(float4*)&out[(size_t)v * 128 + sl * 8] = make_float4(o[0], o[1], o[2], o[3]);
  *(float4*)&out[(size_t)v * 128 + sl * 8 + 4] = make_float4(o[4], o[5], o[6], o[7]);
}

// ---------------- launch ----------------

extern "C" void kernel_launch(void* const* d_in, const int* in_sizes, int n_in,
                              void* d_out, int out_size, void* d_ws, size_t ws_size,
                              hipStream_t stream) {
  const float* x = (const float*)d_in[0];
  const int* ei = (const int*)d_in[1];
  const float* W1 = (const float*)d_in[2];
  const float* b1 = (const float*)d_in[3];
  const float* W2 = (const float*)d_in[4];
  const float* b2 = (const float*)d_in[5];
  float* out = (float*)d_out;

  const int* row = ei;
  const int* col = ei + NE;

  const int NB = (NN + 255) / 256;

  u16* Hb = (u16*)d_ws;                       // [NN,256] bf16, pre-scaled by dinv[row]
  u16* H2b = Hb + (size_t)NN * 256;           // [NN,256] bf16
  u16* H3b = H2b + (size_t)NN * 256;          // [NN,128] bf16, pre-scaled by dinv[row]
  u16* W1t = H3b + (size_t)NN * 128;          // [256,256] bf16
  u16* W2t = W1t + 256 * 256;                 // [128,256] bf16
  int* cnt = (int*)(W2t + 128 * 256);         // [NN]
  int* row_off = cnt + NN;                    // [NN+1]
  int* cursor = row_off + NN + 1;             // [NN]
  float* dinv = (float*)(cursor + NN);        // [NN]
  int* bsum = (int*)(dinv + NN);              // [NB]
  int* boff = bsum + NB;                      // [NB]
  int* csr = boff + NB;                       // [NE] src only

  hipMemsetAsync(cnt, 0, NN * sizeof(int), stream);
  convw_kernel<<<256, 256, 0, stream>>>(W1, W2, W1t, W2t);
  hist_kernel<<<(NE + 255) / 256, 256, 0, stream>>>(col, cnt, NE);
  scan1_kernel<<<NB, 256, 0, stream>>>(cnt, bsum, NN);
  scan2_kernel<<<1, 256, 0, stream>>>(bsum, boff, row_off, NB, NN);
  scan3_kernel<<<NB, 256, 0, stream>>>(cnt, boff, row_off, cursor, dinv, NN);
  scatter_kernel<<<(NE + 255) / 256, 256, 0, stream>>>(row, col, cursor, csr, NE);

  {
    dim3 grid(HID_C / 128, (NN + 127) / 128);
    gemm_mfma<true><<<grid, 256, 0, stream>>>(x, W1t, dinv, Hb, NN, HID_C);
  }
  agg256_bf<<<(NN + 7) / 8, 256, 0, stream>>>(Hb, row_off, csr, dinv, b1, H2b, NN);

  {
    dim3 grid(OUT_C / 128, (NN + 127) / 128);
    gemm_mfma<false><<<grid, 256, 0, stream>>>(H2b, W2t, dinv, H3b, NN, OUT_C);
  }
  agg128_bf<<<(NN + 15) / 16, 256, 0, stream>>>(H3b, row_off, csr, dinv, b2, out, NN);
}

// Round 6
// 303.635 us; speedup vs baseline: 1.0430x; 1.0430x over previous
//
#include <hip/hip_runtime.h>

#define NN 50000
#define NE 800000
#define IN_C 256
#define HID_C 256
#define OUT_C 128

typedef unsigned short u16;
typedef __attribute__((ext_vector_type(8))) short short8;
typedef __attribute__((ext_vector_type(8))) unsigned short ushort8;
typedef __attribute__((ext_vector_type(4))) float f32x4;

__device__ __forceinline__ u16 f2b(float f) {
  unsigned int u = __float_as_uint(f);
  return (u16)((u + 0x7FFFu + ((u >> 16) & 1u)) >> 16);  // RNE
}
__device__ __forceinline__ float b2f(u16 s) {
  return __uint_as_float(((unsigned int)s) << 16);
}

// ---------------- fused: weight convert+transpose AND cnt zeroing ----------------

__global__ __launch_bounds__(256) void convw_zero(const float* __restrict__ W1,
                                                  const float* __restrict__ W2,
                                                  u16* __restrict__ W1t,
                                                  u16* __restrict__ W2t,
                                                  int* __restrict__ cnt) {
  int b = blockIdx.x;
  if (b < 256) {
    int id = b * 256 + threadIdx.x;
    if (id < 256 * 256) {
      int n = id >> 8, k = id & 255;
      W1t[id] = f2b(W1[k * 256 + n]);
    }
    if (id < 128 * 256) {
      int n = id >> 8, k = id & 255;
      W2t[id] = f2b(W2[k * 128 + n]);
    }
  } else {
    int i = (b - 256) * 256 + threadIdx.x;
    if (i < NN) cnt[i] = 0;
  }
}

// ---------------- CSR build ----------------

__global__ __launch_bounds__(256) void hist_kernel(const int* __restrict__ col,
                                                   int* __restrict__ cnt, int E) {
  int e = blockIdx.x * blockDim.x + threadIdx.x;
  if (e < E) atomicAdd(&cnt[col[e]], 1);
}

__global__ __launch_bounds__(256) void scan1_kernel(const int* __restrict__ cnt,
                                                    int* __restrict__ bsum, int n) {
  __shared__ int ws[4];
  int i = blockIdx.x * 256 + threadIdx.x;
  int lane = threadIdx.x & 63, wid = threadIdx.x >> 6;
  int v = (i < n) ? cnt[i] : 0;
#pragma unroll
  for (int off = 32; off > 0; off >>= 1) v += __shfl_down(v, off, 64);
  if (lane == 0) ws[wid] = v;
  __syncthreads();
  if (threadIdx.x == 0) bsum[blockIdx.x] = ws[0] + ws[1] + ws[2] + ws[3];
}

__global__ __launch_bounds__(256) void scan2_kernel(const int* __restrict__ bsum,
                                                    int* __restrict__ boff,
                                                    int* __restrict__ row_off,
                                                    int nb, int n) {
  __shared__ int wsum[4], wpre[5];
  int lane = threadIdx.x & 63, wid = threadIdx.x >> 6;
  int v = (threadIdx.x < nb) ? bsum[threadIdx.x] : 0;
  int s = v;
#pragma unroll
  for (int off = 1; off < 64; off <<= 1) {
    int t = __shfl_up(s, off, 64);
    if (lane >= off) s += t;
  }
  if (lane == 63) wsum[wid] = s;
  __syncthreads();
  if (threadIdx.x == 0) {
    int acc = 0;
#pragma unroll
    for (int w = 0; w < 4; ++w) { wpre[w] = acc; acc += wsum[w]; }
    wpre[4] = acc;
  }
  __syncthreads();
  if (threadIdx.x < nb) boff[threadIdx.x] = wpre[wid] + (s - v);
  if (threadIdx.x == 0) row_off[n] = wpre[4];
}

__global__ __launch_bounds__(256) void scan3_kernel(const int* __restrict__ cnt,
                                                    const int* __restrict__ boff,
                                                    int* __restrict__ row_off,
                                                    int* __restrict__ cursor,
                                                    float* __restrict__ dinv, int n) {
  __shared__ int wsum[4], wpre[4];
  int i = blockIdx.x * 256 + threadIdx.x;
  int lane = threadIdx.x & 63, wid = threadIdx.x >> 6;
  int v = (i < n) ? cnt[i] : 0;
  int s = v;
#pragma unroll
  for (int off = 1; off < 64; off <<= 1) {
    int t = __shfl_up(s, off, 64);
    if (lane >= off) s += t;
  }
  if (lane == 63) wsum[wid] = s;
  __syncthreads();
  if (threadIdx.x == 0) {
    int acc = 0;
#pragma unroll
    for (int w = 0; w < 4; ++w) { wpre[w] = acc; acc += wsum[w]; }
  }
  __syncthreads();
  if (i < n) {
    int off = boff[blockIdx.x] + wpre[wid] + (s - v);
    row_off[i] = off;
    cursor[i] = off;
    dinv[i] = rsqrtf((float)(v + 1));
  }
}

// ---------------- MFMA GEMM body (shared by plain and fused kernels) ----------------
// C[r,:]bf16 = dscale[r] * (A[r,:] @ Bt^T).  BM=BN=128, BK=32, 4 waves 2x2,
// register-prefetch + double-buffered LDS, one barrier per K-iter.

template <bool A_IS_F32>
__device__ __forceinline__ void gemm_body(const void* __restrict__ Ap,
                                          const u16* __restrict__ Bt,
                                          const float* __restrict__ dscale,
                                          u16* __restrict__ C, int M, int N,
                                          int bx, int by,
                                          u16 (&Asl)[2][5120], u16 (&Bsl)[2][5120]) {
  const int tid = threadIdx.x;
  const int row0 = by * 128;
  const int col0 = bx * 128;

  f32x4 acc[4][4] = {};

  const int seg = tid & 7;
  const int rb = tid >> 3;
  const int wave = tid >> 6, lane = tid & 63;
  const int wm = wave >> 1, wn = wave & 1;
  const int qr = lane & 15, quad = lane >> 4;

  float4 aF[4];
  ushort4 aU[4];
  ushort4 bR[4];

  auto load_tiles = [&](int k0) {
    if constexpr (A_IS_F32) {
      const float* A = (const float*)Ap;
#pragma unroll
      for (int i = 0; i < 4; ++i) {
        int gr = row0 + rb + i * 32;
        aF[i] = (gr < M) ? *(const float4*)&A[(size_t)gr * 256 + k0 + seg * 4]
                         : make_float4(0.f, 0.f, 0.f, 0.f);
      }
    } else {
      const u16* A = (const u16*)Ap;
#pragma unroll
      for (int i = 0; i < 4; ++i) {
        int gr = row0 + rb + i * 32;
        aU[i] = (gr < M) ? *(const ushort4*)&A[(size_t)gr * 256 + k0 + seg * 4]
                         : make_ushort4(0, 0, 0, 0);
      }
    }
#pragma unroll
    for (int i = 0; i < 4; ++i) {
      int n = rb + i * 32;
      bR[i] = *(const ushort4*)&Bt[(size_t)(col0 + n) * 256 + k0 + seg * 4];
    }
  };

  auto write_lds = [&](int buf) {
#pragma unroll
    for (int i = 0; i < 4; ++i) {
      int r = rb + i * 32;
      ushort4 u;
      if constexpr (A_IS_F32) {
        u.x = f2b(aF[i].x); u.y = f2b(aF[i].y);
        u.z = f2b(aF[i].z); u.w = f2b(aF[i].w);
      } else {
        u = aU[i];
      }
      *(ushort4*)&Asl[buf][r * 40 + seg * 4] = u;
      *(ushort4*)&Bsl[buf][r * 40 + seg * 4] = bR[i];
    }
  };

  load_tiles(0);
  write_lds(0);
  __syncthreads();

#pragma unroll
  for (int it = 0; it < 8; ++it) {
    const int cur = it & 1;
    if (it < 7) load_tiles((it + 1) * 32);

    short8 afr[4], bfr[4];
#pragma unroll
    for (int mt = 0; mt < 4; ++mt)
      afr[mt] = *(const short8*)&Asl[cur][(wm * 64 + mt * 16 + qr) * 40 + quad * 8];
#pragma unroll
    for (int nt = 0; nt < 4; ++nt)
      bfr[nt] = *(const short8*)&Bsl[cur][(wn * 64 + nt * 16 + qr) * 40 + quad * 8];
#pragma unroll
    for (int mt = 0; mt < 4; ++mt)
#pragma unroll
      for (int nt = 0; nt < 4; ++nt)
        acc[mt][nt] = __builtin_amdgcn_mfma_f32_16x16x32_bf16(afr[mt], bfr[nt], acc[mt][nt], 0, 0, 0);

    if (it < 7) {
      write_lds(1 - cur);
      __syncthreads();
    }
  }

#pragma unroll
  for (int mt = 0; mt < 4; ++mt) {
#pragma unroll
    for (int i = 0; i < 4; ++i) {
      int gr = row0 + wm * 64 + mt * 16 + quad * 4 + i;
      if (gr < M) {
        float sc = dscale[gr];
#pragma unroll
        for (int nt = 0; nt < 4; ++nt) {
          int gc = col0 + wn * 64 + nt * 16 + qr;
          C[(size_t)gr * N + gc] = f2b(acc[mt][nt][i] * sc);
        }
      }
    }
  }
}

// plain GEMM kernel (layer 2)
template <bool A_IS_F32>
__global__ __launch_bounds__(256) void gemm_mfma(const void* __restrict__ Ap,
                                                 const u16* __restrict__ Bt,
                                                 const float* __restrict__ dscale,
                                                 u16* __restrict__ C, int M, int N) {
  __shared__ u16 Asl[2][5120];
  __shared__ u16 Bsl[2][5120];
  gemm_body<A_IS_F32>(Ap, Bt, dscale, C, M, N, blockIdx.x, blockIdx.y, Asl, Bsl);
}

// fused: GEMM1 (blocks [0,ngb)) + edge scatter (blocks [ngb, ngb+nsb))
__global__ __launch_bounds__(256) void gemm1_scatter(const float* __restrict__ x,
                                                     const u16* __restrict__ W1t,
                                                     const float* __restrict__ dinv,
                                                     u16* __restrict__ Hb, int M, int N,
                                                     int ngb,
                                                     const int* __restrict__ row,
                                                     const int* __restrict__ col,
                                                     int* __restrict__ cursor,
                                                     int* __restrict__ csr, int E) {
  __shared__ u16 Asl[2][5120];
  __shared__ u16 Bsl[2][5120];
  int b = blockIdx.x;
  if (b < ngb) {
    gemm_body<true>(x, W1t, dinv, Hb, M, N, b & 1, b >> 1, Asl, Bsl);
  } else {
    int e = (b - ngb) * 256 + threadIdx.x;
    if (e < E) {
      int c = col[e];
      int p = atomicAdd(&cursor[c], 1);
      csr[p] = row[e];
    }
  }
}

// ---------------- aggregation: weightless sum of pre-scaled rows ----------------
// out[v] = dinv[v] * (sum_{src in N(v)} Hs[src] + Hs[v]) + bias   (+ optional relu)

// 256 ch: 2 nodes/wave, 32 lanes x 8 ch, 8 outstanding gathers, int4 index loads
__global__ __launch_bounds__(256) void agg256_bf(const u16* __restrict__ h,
                                                 const int* __restrict__ row_off,
                                                 const int* __restrict__ csr,
                                                 const float* __restrict__ dinv,
                                                 const float* __restrict__ bias,
                                                 u16* __restrict__ out, int n) {
  int wave = threadIdx.x >> 6;
  int lane = threadIdx.x & 63;
  int half = lane >> 5;
  int sl = lane & 31;
  int v = blockIdx.x * 8 + wave * 2 + half;
  if (v >= n) return;
  int beg = row_off[v], end = row_off[v + 1];
  float a[8] = {};
  int e = beg;
  // align e to 4-index boundary for int4 loads
  for (; e < end && (e & 3); ++e) {
    int s0 = csr[e];
    ushort8 g0 = *(const ushort8*)&h[(size_t)s0 * 256 + sl * 8];
#pragma unroll
    for (int i = 0; i < 8; ++i) a[i] += b2f((u16)g0[i]);
  }
  for (; e + 7 < end; e += 8) {
    int4 i0 = *(const int4*)&csr[e];
    int4 i1 = *(const int4*)&csr[e + 4];
    int s[8] = {i0.x, i0.y, i0.z, i0.w, i1.x, i1.y, i1.z, i1.w};
    ushort8 g[8];
#pragma unroll
    for (int j = 0; j < 8; ++j)
      g[j] = *(const ushort8*)&h[(size_t)s[j] * 256 + sl * 8];
#pragma unroll
    for (int j = 0; j < 8; ++j)
#pragma unroll
      for (int i = 0; i < 8; ++i) a[i] += b2f((u16)g[j][i]);
  }
  for (; e < end; ++e) {
    int s0 = csr[e];
    ushort8 g0 = *(const ushort8*)&h[(size_t)s0 * 256 + sl * 8];
#pragma unroll
    for (int i = 0; i < 8; ++i) a[i] += b2f((u16)g0[i]);
  }
  ushort8 hs = *(const ushort8*)&h[(size_t)v * 256 + sl * 8];
#pragma unroll
  for (int i = 0; i < 8; ++i) a[i] += b2f((u16)hs[i]);
  float dv = dinv[v];
  float4 bv0 = *(const float4*)&bias[sl * 8];
  float4 bv1 = *(const float4*)&bias[sl * 8 + 4];
  float bb[8] = {bv0.x, bv0.y, bv0.z, bv0.w, bv1.x, bv1.y, bv1.z, bv1.w};
  ushort8 o;
#pragma unroll
  for (int i = 0; i < 8; ++i) {
    float r = fmaxf(a[i] * dv + bb[i], 0.f);
    o[i] = (short)f2b(r);
  }
  *(ushort8*)&out[(size_t)v * 256 + sl * 8] = o;
}

// 128 ch: 4 nodes/wave, 16 lanes x 8 ch, 8 outstanding gathers; fp32 out, no relu
__global__ __launch_bounds__(256) void agg128_bf(const u16* __restrict__ h,
                                                 const int* __restrict__ row_off,
                                                 const int* __restrict__ csr,
                                                 const float* __restrict__ dinv,
                                                 const float* __restrict__ bias,
                                                 float* __restrict__ out, int n) {
  int wave = threadIdx.x >> 6;
  int lane = threadIdx.x & 63;
  int quarter = lane >> 4;
  int sl = lane & 15;
  int v = blockIdx.x * 16 + wave * 4 + quarter;
  if (v >= n) return;
  int beg = row_off[v], end = row_off[v + 1];
  float a[8] = {};
  int e = beg;
  for (; e < end && (e & 3); ++e) {
    int s0 = csr[e];
    ushort8 g0 = *(const ushort8*)&h[(size_t)s0 * 128 + sl * 8];
#pragma unroll
    for (int i = 0; i < 8; ++i) a[i] += b2f((u16)g0[i]);
  }
  for (; e + 7 < end; e += 8) {
    int4 i0 = *(const int4*)&csr[e];
    int4 i1 = *(const int4*)&csr[e + 4];
    int s[8] = {i0.x, i0.y, i0.z, i0.w, i1.x, i1.y, i1.z, i1.w};
    ushort8 g[8];
#pragma unroll
    for (int j = 0; j < 8; ++j)
      g[j] = *(const ushort8*)&h[(size_t)s[j] * 128 + sl * 8];
#pragma unroll
    for (int j = 0; j < 8; ++j)
#pragma unroll
      for (int i = 0; i < 8; ++i) a[i] += b2f((u16)g[j][i]);
  }
  for (; e < end; ++e) {
    int s0 = csr[e];
    ushort8 g0 = *(const ushort8*)&h[(size_t)s0 * 128 + sl * 8];
#pragma unroll
    for (int i = 0; i < 8; ++i) a[i] += b2f((u16)g0[i]);
  }
  ushort8 hs = *(const ushort8*)&h[(size_t)v * 128 + sl * 8];
#pragma unroll
  for (int i = 0; i < 8; ++i) a[i] += b2f((u16)hs[i]);
  float dv = dinv[v];
  float4 bv0 = *(const float4*)&bias[sl * 8];
  float4 bv1 = *(const float4*)&bias[sl * 8 + 4];
  float bb[8] = {bv0.x, bv0.y, bv0.z, bv0.w, bv1.x, bv1.y, bv1.z, bv1.w};
  float o[8];
#pragma unroll
  for (int i = 0; i < 8; ++i) o[i] = a[i] * dv + bb[i];
  *(float4*)&out[(size_t)v * 128 + sl * 8] = make_float4(o[0], o[1], o[2], o[3]);
  *(float4*)&out[(size_t)v * 128 + sl * 8 + 4] = make_float4(o[4], o[5], o[6], o[7]);
}

// ---------------- launch ----------------

extern "C" void kernel_launch(void* const* d_in, const int* in_sizes, int n_in,
                              void* d_out, int out_size, void* d_ws, size_t ws_size,
                              hipStream_t stream) {
  const float* x = (const float*)d_in[0];
  const int* ei = (const int*)d_in[1];
  const float* W1 = (const float*)d_in[2];
  const float* b1 = (const float*)d_in[3];
  const float* W2 = (const float*)d_in[4];
  const float* b2 = (const float*)d_in[5];
  float* out = (float*)d_out;

  const int* row = ei;
  const int* col = ei + NE;

  const int NB = (NN + 255) / 256;  // 196

  // workspace layout — all arrays padded so csr is 16B-aligned
  u16* Hb = (u16*)d_ws;                       // [NN,256] bf16, pre-scaled by dinv[row]
  u16* H2b = Hb + (size_t)NN * 256;           // [NN,256] bf16
  u16* H3b = H2b + (size_t)NN * 256;          // [NN,128] bf16, pre-scaled
  u16* W1t = H3b + (size_t)NN * 128;          // [256,256] bf16
  u16* W2t = W1t + 256 * 256;                 // [128,256] bf16
  int* cnt = (int*)(W2t + 128 * 256);         // [NN]
  int* row_off = cnt + NN;                    // [NN+4] (padded)
  int* cursor = row_off + NN + 4;             // [NN]
  float* dinv = (float*)(cursor + NN);        // [NN]
  int* bsum = (int*)(dinv + NN);              // [200]
  int* boff = bsum + 200;                     // [200]
  int* csr = boff + 200;                      // [NE] src only, 16B-aligned

  convw_zero<<<256 + NB, 256, 0, stream>>>(W1, W2, W1t, W2t, cnt);
  hist_kernel<<<(NE + 255) / 256, 256, 0, stream>>>(col, cnt, NE);
  scan1_kernel<<<NB, 256, 0, stream>>>(cnt, bsum, NN);
  scan2_kernel<<<1, 256, 0, stream>>>(bsum, boff, row_off, NB, NN);
  scan3_kernel<<<NB, 256, 0, stream>>>(cnt, boff, row_off, cursor, dinv, NN);

  // fused: GEMM1 (Hb = dinv * (x@W1), bf16) concurrent with edge scatter
  {
    const int ngb = (HID_C / 128) * ((NN + 127) / 128);  // 782
    const int nsb = (NE + 255) / 256;                    // 3125
    gemm1_scatter<<<ngb + nsb, 256, 0, stream>>>(x, W1t, dinv, Hb, NN, HID_C, ngb,
                                                 row, col, cursor, csr, NE);
  }
  agg256_bf<<<(NN + 7) / 8, 256, 0, stream>>>(Hb, row_off, csr, dinv, b1, H2b, NN);

  {
    dim3 grid(OUT_C / 128, (NN + 127) / 128);
    gemm_mfma<false><<<grid, 256, 0, stream>>>(H2b, W2t, dinv, H3b, NN, OUT_C);
  }
  agg128_bf<<<(NN + 15) / 16, 256, 0, stream>>>(H3b, row_off, csr, dinv, b2, out, NN);
}